// Round 7
// baseline (526.784 us; speedup 1.0000x reference)
//
#include <hip/hip_runtime.h>
#include <hip/hip_bf16.h>
#include <stdint.h>

// QuantizedLinear: out = (Q(x)-zp) @ W^T * (IN_SCALE*W_SCALE) + b*1e-4
// T=8192, Din=Dout=4096. Fast path: exact integer GEMM via mfma_i32_16x16x64_i8
// (needs ~50.4MB of d_ws). Fallback (ws too small): fused-quant f32 GEMM, ws-free.
// zp computed from the Python: round(1/(2/255+1e-12)) = 127 (the "# 128" comment is stale).
// R6 fix: prep_w row indexing was it*1024+t (OOB reads past w's end -> memory fault,
// the cause of the R3/R6 core dumps); correct stride is 256 -> idx = it*256 + t.

#define TOKENS 8192
#define DIN    4096
#define DOUT   4096

typedef int v4i __attribute__((ext_vector_type(4)));

#define IN_SCALE_F ((float)(2.0/255.0))
#define SF  ((float)((2.0/255.0)*0.01))   // IN_SCALE*W_SCALE
#define BSF (1e-4f)

// ---------- address-space helpers for global_load_lds ----------
typedef const __attribute__((address_space(1))) void* gas_ptr;
typedef __attribute__((address_space(3))) void* las_ptr;
#define GLL16(g, s) __builtin_amdgcn_global_load_lds((gas_ptr)(g), (las_ptr)(s), 16, 0, 0)

// ---------------- quantize X: f32 -> int8 (x_q - 128) ----------------
__device__ __forceinline__ int quant1(float x) {
    float v = rintf(x / IN_SCALE_F + 127.0f);   // round-half-even, zp=127
    v = fminf(fmaxf(v, 0.0f), 255.0f);          // clip to uint8 range
    return (int)v - 128;                        // store shifted by 128 -> int8
}

__global__ void quant_x(const float* __restrict__ x, signed char* __restrict__ xq) {
    const int n4 = TOKENS * DIN / 4;
    const float4* x4 = (const float4*)x;
    int* o4 = (int*)xq;
    int i = blockIdx.x * blockDim.x + threadIdx.x;
    int stride = gridDim.x * blockDim.x;
    for (; i < n4; i += stride) {
        float4 v = x4[i];
        int q0 = quant1(v.x), q1 = quant1(v.y), q2 = quant1(v.z), q3 = quant1(v.w);
        o4[i] = (q0 & 255) | ((q1 & 255) << 8) | ((q2 & 255) << 16) | ((q3 & 255) << 24);
    }
}

// ------------- prep W: f32 -> int8, row sums -> beta -------------
// beta[o] = rowsum(W[o,:]) * SF + b[o] * BSF   (corrects the -128 shift)
__global__ void prep_w(const float* __restrict__ w, const float* __restrict__ bq,
                       signed char* __restrict__ wq, float* __restrict__ beta) {
    int row = blockIdx.x, t = threadIdx.x;
    const float4* wrow = (const float4*)(w + (size_t)row * DIN);
    int* wqrow = (int*)(wq + (size_t)row * DIN);
    int s = 0;
#pragma unroll
    for (int it = 0; it < 4; ++it) {
        int idx = it * 256 + t;                  // R6 FIX: stride 256, covers 0..1023 exactly
        float4 v = wrow[idx];
        int a0 = (int)v.x, a1 = (int)v.y, a2 = (int)v.z, a3 = (int)v.w;
        s += a0 + a1 + a2 + a3;
        wqrow[idx] = (a0 & 255) | ((a1 & 255) << 8) | ((a2 & 255) << 16) | ((a3 & 255) << 24);
    }
#pragma unroll
    for (int off = 32; off > 0; off >>= 1) s += __shfl_down(s, off);
    __shared__ int red[4];
    if ((t & 63) == 0) red[t >> 6] = s;
    __syncthreads();
    if (t == 0) beta[row] = (float)(red[0] + red[1] + red[2] + red[3]) * SF + bq[row] * BSF;
}

// ---------------- fast path i8 GEMM (m97 structure) ----------------
#define BM 128
#define BN 128
#define BK 64

__global__ __launch_bounds__(256) void gemm_i8(const signed char* __restrict__ A,
                                               const signed char* __restrict__ B,
                                               const float* __restrict__ beta,
                                               float* __restrict__ out) {
    __shared__ signed char lds[16384];          // A tile 8KB @0, B tile 8KB @8192
    const int t = threadIdx.x;
    const int w = t >> 6, l = t & 63;

    const int bid = blockIdx.x;                 // 2048 blocks, %8==0 -> bijective swizzle
    const int swz = (bid & 7) * 256 + (bid >> 3);
    const int bm = swz >> 5;
    const int bn = swz & 31;
    const int m0 = bm * BM, n0 = bn * BN;

    const int wr = (w >> 1) * 64;
    const int wc = (w & 1) * 64;

    const signed char* a_src0 = A + (size_t)(m0 + l) * DIN + w * 16;
    const signed char* a_src1 = A + (size_t)(m0 + 64 + l) * DIN + w * 16;
    const signed char* b_src0 = B + (size_t)(n0 + l) * DIN + w * 16;
    const signed char* b_src1 = B + (size_t)(n0 + 64 + l) * DIN + w * 16;
    const unsigned ldsOffA0 = w * 2048 + l * 16;
    const unsigned ldsOffA1 = w * 2048 + 1024 + l * 16;

    const unsigned aoff = (unsigned)((l >> 4) * 2048 + (wr + (l & 15)) * 16);
    const unsigned boff = (unsigned)(8192 + (l >> 4) * 2048 + (wc + (l & 15)) * 16);

    v4i acc[4][4];
#pragma unroll
    for (int mi = 0; mi < 4; ++mi)
#pragma unroll
        for (int ni = 0; ni < 4; ++ni) acc[mi][ni] = (v4i)0;

    for (int k0 = 0; k0 < DIN; k0 += BK) {
        GLL16(a_src0 + k0, lds + ldsOffA0);
        GLL16(a_src1 + k0, lds + ldsOffA1);
        GLL16(b_src0 + k0, lds + 8192 + ldsOffA0);
        GLL16(b_src1 + k0, lds + 8192 + ldsOffA1);
        __syncthreads();

        v4i af[4], bf[4];
#pragma unroll
        for (int i = 0; i < 4; ++i) af[i] = *(const v4i*)(lds + aoff + i * 256);
#pragma unroll
        for (int i = 0; i < 4; ++i) bf[i] = *(const v4i*)(lds + boff + i * 256);
#pragma unroll
        for (int mi = 0; mi < 4; ++mi)
#pragma unroll
            for (int ni = 0; ni < 4; ++ni)
                acc[mi][ni] = __builtin_amdgcn_mfma_i32_16x16x64_i8(af[mi], bf[ni], acc[mi][ni], 0, 0, 0);
        __syncthreads();
    }

    const int col0 = n0 + wc + (l & 15);
    const int row0 = m0 + wr + (l >> 4) * 4;
#pragma unroll
    for (int ni = 0; ni < 4; ++ni) {
        const float bb = beta[col0 + ni * 16];
#pragma unroll
        for (int mi = 0; mi < 4; ++mi) {
#pragma unroll
            for (int r = 0; r < 4; ++r) {
                out[(size_t)(row0 + mi * 16 + r) * DOUT + (col0 + ni * 16)] =
                    (float)acc[mi][ni][r] * SF + bb;
            }
        }
    }
}

// ---------------- ws-free fallback: fused-quant f32 GEMM ----------------
__global__ __launch_bounds__(256) void gemm_fb(const float* __restrict__ x,
                                               const float* __restrict__ wgt,
                                               const float* __restrict__ bq,
                                               float* __restrict__ out) {
    __shared__ float As[64][33];
    __shared__ float Bs[64][33];
    const int t = threadIdx.x;
    const int bn = blockIdx.x & 63;
    const int bm = blockIdx.x >> 6;
    const int m0 = bm * 64, n0 = bn * 64;
    const int ty = t >> 4, tx = t & 15;

    float acc[4][4] = {{0.f}};

    for (int k0 = 0; k0 < DIN; k0 += 32) {
#pragma unroll
        for (int i = 0; i < 8; ++i) {
            int li = t * 8 + i;
            int r = li >> 5, c = li & 31;
            float v = x[(size_t)(m0 + r) * DIN + k0 + c];
            float q = fminf(fmaxf(rintf(v / IN_SCALE_F + 127.0f), 0.0f), 255.0f) - 127.0f;
            As[r][c] = q;
            Bs[r][c] = wgt[(size_t)(n0 + r) * DIN + k0 + c];
        }
        __syncthreads();
#pragma unroll 8
        for (int k = 0; k < 32; ++k) {
            float a0 = As[ty * 4 + 0][k], a1 = As[ty * 4 + 1][k];
            float a2 = As[ty * 4 + 2][k], a3 = As[ty * 4 + 3][k];
            float b0 = Bs[tx * 4 + 0][k], b1 = Bs[tx * 4 + 1][k];
            float b2 = Bs[tx * 4 + 2][k], b3 = Bs[tx * 4 + 3][k];
            acc[0][0] += a0 * b0; acc[0][1] += a0 * b1; acc[0][2] += a0 * b2; acc[0][3] += a0 * b3;
            acc[1][0] += a1 * b0; acc[1][1] += a1 * b1; acc[1][2] += a1 * b2; acc[1][3] += a1 * b3;
            acc[2][0] += a2 * b0; acc[2][1] += a2 * b1; acc[2][2] += a2 * b2; acc[2][3] += a2 * b3;
            acc[3][0] += a3 * b0; acc[3][1] += a3 * b1; acc[3][2] += a3 * b2; acc[3][3] += a3 * b3;
        }
        __syncthreads();
    }

#pragma unroll
    for (int i = 0; i < 4; ++i)
#pragma unroll
        for (int j = 0; j < 4; ++j) {
            int col = n0 + tx * 4 + j;
            out[(size_t)(m0 + ty * 4 + i) * DOUT + col] = acc[i][j] * SF + bq[col] * BSF;
        }
}

extern "C" void kernel_launch(void* const* d_in, const int* in_sizes, int n_in,
                              void* d_out, int out_size, void* d_ws, size_t ws_size,
                              hipStream_t stream) {
    const float* x = (const float*)d_in[0];   // [8192,4096] f32
    const float* wgt = (const float*)d_in[1]; // [4096,4096] f32 (integer-valued)
    const float* bq = (const float*)d_in[2];  // [4096] f32 (integer-valued)
    float* out = (float*)d_out;

    const size_t need = (size_t)TOKENS * DIN + (size_t)DOUT * DIN + (size_t)DOUT * sizeof(float);

    if (d_ws != nullptr && ws_size >= need) {
        signed char* xq = (signed char*)d_ws;
        signed char* wq = xq + (size_t)TOKENS * DIN;
        float* beta = (float*)(wq + (size_t)DOUT * DIN);

        quant_x<<<2048, 256, 0, stream>>>(x, xq);
        prep_w<<<DOUT, 256, 0, stream>>>(wgt, bq, wq, beta);
        gemm_i8<<<(TOKENS / BM) * (DOUT / BN), 256, 0, stream>>>(xq, wq, beta, out);
    } else {
        gemm_fb<<<(TOKENS / 64) * (DOUT / 64), 256, 0, stream>>>(x, wgt, bq, out);
    }
}

// Round 8
// 408.297 us; speedup vs baseline: 1.2902x; 1.2902x over previous
//
#include <hip/hip_runtime.h>
#include <hip/hip_bf16.h>
#include <stdint.h>

// QuantizedLinear: out = (Q(x)-zp) @ W^T * (IN_SCALE*W_SCALE) + b*1e-4
// R8: gemm restructured 128^2 -> 256^2 tile (halves staged bytes: 2.15GB -> 1.07GB,
// the measured bottleneck: MfmaUtil 20%, staging feed ~7.5 TB/s) with a 4-deep
// LDS ring + counted vmcnt(12) pipeline (stage tile t+3 while computing tile t).

#define TOKENS 8192
#define DIN    4096
#define DOUT   4096

typedef int v4i __attribute__((ext_vector_type(4)));

#define IN_SCALE_F ((float)(2.0/255.0))
#define SF  ((float)((2.0/255.0)*0.01))   // IN_SCALE*W_SCALE
#define BSF (1e-4f)

typedef const __attribute__((address_space(1))) void* gas_ptr;
typedef __attribute__((address_space(3))) void* las_ptr;
#define GLL16(g, s) __builtin_amdgcn_global_load_lds((gas_ptr)(g), (las_ptr)(s), 16, 0, 0)

// ---------------- quantize X: f32 -> int8 (x_q - 128) ----------------
__device__ __forceinline__ int quant1(float x) {
    float v = rintf(x / IN_SCALE_F + 127.0f);   // round-half-even, zp=127
    v = fminf(fmaxf(v, 0.0f), 255.0f);
    return (int)v - 128;
}

__global__ void quant_x(const float* __restrict__ x, signed char* __restrict__ xq) {
    const int n4 = TOKENS * DIN / 4;
    const float4* x4 = (const float4*)x;
    int* o4 = (int*)xq;
    int i = blockIdx.x * blockDim.x + threadIdx.x;
    int stride = gridDim.x * blockDim.x;
    for (; i < n4; i += stride) {
        float4 v = x4[i];
        int q0 = quant1(v.x), q1 = quant1(v.y), q2 = quant1(v.z), q3 = quant1(v.w);
        o4[i] = (q0 & 255) | ((q1 & 255) << 8) | ((q2 & 255) << 16) | ((q3 & 255) << 24);
    }
}

// ------------- prep W: f32 -> int8, row sums -> beta -------------
__global__ void prep_w(const float* __restrict__ w, const float* __restrict__ bq,
                       signed char* __restrict__ wq, float* __restrict__ beta) {
    int row = blockIdx.x, t = threadIdx.x;
    const float4* wrow = (const float4*)(w + (size_t)row * DIN);
    int* wqrow = (int*)(wq + (size_t)row * DIN);
    int s = 0;
#pragma unroll
    for (int it = 0; it < 4; ++it) {
        int idx = it * 256 + t;                  // covers 0..1023
        float4 v = wrow[idx];
        int a0 = (int)v.x, a1 = (int)v.y, a2 = (int)v.z, a3 = (int)v.w;
        s += a0 + a1 + a2 + a3;
        wqrow[idx] = (a0 & 255) | ((a1 & 255) << 8) | ((a2 & 255) << 16) | ((a3 & 255) << 24);
    }
#pragma unroll
    for (int off = 32; off > 0; off >>= 1) s += __shfl_down(s, off);
    __shared__ int red[4];
    if ((t & 63) == 0) red[t >> 6] = s;
    __syncthreads();
    if (t == 0) beta[row] = (float)(red[0] + red[1] + red[2] + red[3]) * SF + bq[row] * BSF;
}

// ---------------- i8 GEMM: 256x256 tile, BK=64, 4-deep LDS ring ----------------
// 512 threads = 8 waves (2M x 4N), per-wave output 128x64 = 8x4 frags of 16x16.
// LDS: 4 ring buffers x (A 16KB + B 16KB) = 128 KB. Stage tile t+3 while computing t.
// One counted vmcnt(12) per iter (3 tiles x 4 loads/thread in flight) - never 0.
// Swizzle: 64-B rows, 16-B slot s stored at s^(row&3); global source pre-swizzled,
// LDS dest linear (global_load_lds constraint), read applies same XOR.
#define BM 256
#define BN 256
#define BKI 64
#define NT (DIN / BKI)          // 64 K-tiles
#define BUFB 32768              // bytes per ring buffer (A 16K + B 16K)

__global__ __launch_bounds__(512, 1) void gemm_i8(const signed char* __restrict__ A,
                                                  const signed char* __restrict__ B,
                                                  const float* __restrict__ beta,
                                                  float* __restrict__ out) {
    __shared__ signed char lds[4 * BUFB];       // 128 KB
    const int tid = threadIdx.x;
    const int w = tid >> 6, l = tid & 63;
    const int wm = w >> 2, wn = w & 3;          // wave grid 2M x 4N

    // XCD-aware bijective swizzle: 512 blocks, 512 % 8 == 0
    const int bid = blockIdx.x;
    const int swz = (bid & 7) * 64 + (bid >> 3);
    const int bm = swz >> 4;                    // 32 M-tiles
    const int bn = swz & 15;                    // 16 N-tiles
    const int m0 = bm * BM, n0 = bn * BN;

    // ---- staging geometry (per thread, 2 GLL per matrix per tile) ----
    // call j: linear idx = j*512 + tid; row = idx>>2, slot = idx&3 (16B slots, 64B rows)
    const int row0 = tid >> 2, slot0 = tid & 3;
    const size_t src0 = (size_t)row0 * DIN + (size_t)((slot0 ^ (row0 & 3)) * 16);
    const size_t src1 = src0 + (size_t)128 * DIN;   // row0+128: same &3 -> same xor
    const unsigned l0 = (unsigned)tid * 16;          // linear LDS dest, call 0
    const unsigned l1 = 8192 + (unsigned)tid * 16;   // call 1
    const signed char* Abase = A + (size_t)m0 * DIN;
    const signed char* Bbase = B + (size_t)n0 * DIN;

#define STAGE(tb, kk) do {                                        \
        const signed char* _a = Abase + (kk);                     \
        const signed char* _b = Bbase + (kk);                     \
        signed char* _l = lds + (tb) * BUFB;                      \
        GLL16(_a + src0, _l + l0);                                \
        GLL16(_a + src1, _l + l1);                                \
        GLL16(_b + src0, _l + 16384 + l0);                        \
        GLL16(_b + src1, _l + 16384 + l1);                        \
    } while (0)

    // ---- fragment read offsets (swizzled): xor term constant per lane ----
    const int xslot = (l >> 4) ^ (l & 3);                 // (row&3) == (l&3) for 16-mult frag rows
    const unsigned abase = (unsigned)(wm * 8192 + (l & 15) * 64 + xslot * 16);
    const unsigned bbase = (unsigned)(16384 + wn * 4096 + (l & 15) * 64 + xslot * 16);

    v4i acc[8][4];
#pragma unroll
    for (int mf = 0; mf < 8; ++mf)
#pragma unroll
        for (int nf = 0; nf < 4; ++nf) acc[mf][nf] = (v4i)0;

    // prologue: stage tiles 0,1,2 (12 loads/thread in flight)
    STAGE(0, 0);
    STAGE(1, BKI);
    STAGE(2, 2 * BKI);

#pragma unroll 4
    for (int t = 0; t < NT; ++t) {
        // stage tile t+3 into the buffer last read at t-1 (safe: issued after bar2(t-1))
        const int ts = t + 3;
        STAGE(ts & 3, (ts & (NT - 1)) * BKI);   // wrap at tail: in-bounds, data unused

        // tile t's loads (issued 3 iters ago) must land; allow 3 tiles x 4 loads in flight
        asm volatile("s_waitcnt vmcnt(12)" ::: "memory");
        __builtin_amdgcn_s_barrier();           // all waves' tile-t slices landed
        __builtin_amdgcn_sched_barrier(0);      // pin: no ds_read hoisted above barrier

        const signed char* Lc = lds + (t & 3) * BUFB;
        v4i af[8], bf[4];
#pragma unroll
        for (int mf = 0; mf < 8; ++mf) af[mf] = *(const v4i*)(Lc + abase + mf * 1024);
#pragma unroll
        for (int nf = 0; nf < 4; ++nf) bf[nf] = *(const v4i*)(Lc + bbase + nf * 1024);

        __builtin_amdgcn_s_setprio(1);
#pragma unroll
        for (int mf = 0; mf < 8; ++mf)
#pragma unroll
            for (int nf = 0; nf < 4; ++nf)
                acc[mf][nf] = __builtin_amdgcn_mfma_i32_16x16x64_i8(af[mf], bf[nf], acc[mf][nf], 0, 0, 0);
        __builtin_amdgcn_s_setprio(0);

        __builtin_amdgcn_s_barrier();           // all reads of buf[t&3] done before restage
        __builtin_amdgcn_sched_barrier(0);      // pin: no next-iter GLL hoisted above
    }
#undef STAGE

    // epilogue: D[row=(l>>4)*4+r][col=l&15] per 16x16 frag
    const int col0 = n0 + wn * 64 + (l & 15);
    const int row0o = m0 + wm * 128 + (l >> 4) * 4;
#pragma unroll
    for (int nf = 0; nf < 4; ++nf) {
        const float bb = beta[col0 + nf * 16];
#pragma unroll
        for (int mf = 0; mf < 8; ++mf) {
#pragma unroll
            for (int r = 0; r < 4; ++r) {
                out[(size_t)(row0o + mf * 16 + r) * DOUT + (col0 + nf * 16)] =
                    (float)acc[mf][nf][r] * SF + bb;
            }
        }
    }
}

// ---------------- ws-free fallback: fused-quant f32 GEMM ----------------
__global__ __launch_bounds__(256) void gemm_fb(const float* __restrict__ x,
                                               const float* __restrict__ wgt,
                                               const float* __restrict__ bq,
                                               float* __restrict__ out) {
    __shared__ float As[64][33];
    __shared__ float Bs[64][33];
    const int t = threadIdx.x;
    const int bn = blockIdx.x & 63;
    const int bm = blockIdx.x >> 6;
    const int m0 = bm * 64, n0 = bn * 64;
    const int ty = t >> 4, tx = t & 15;

    float acc[4][4] = {{0.f}};

    for (int k0 = 0; k0 < DIN; k0 += 32) {
#pragma unroll
        for (int i = 0; i < 8; ++i) {
            int li = t * 8 + i;
            int r = li >> 5, c = li & 31;
            float v = x[(size_t)(m0 + r) * DIN + k0 + c];
            float q = fminf(fmaxf(rintf(v / IN_SCALE_F + 127.0f), 0.0f), 255.0f) - 127.0f;
            As[r][c] = q;
            Bs[r][c] = wgt[(size_t)(n0 + r) * DIN + k0 + c];
        }
        __syncthreads();
#pragma unroll 8
        for (int k = 0; k < 32; ++k) {
            float a0 = As[ty * 4 + 0][k], a1 = As[ty * 4 + 1][k];
            float a2 = As[ty * 4 + 2][k], a3 = As[ty * 4 + 3][k];
            float b0 = Bs[tx * 4 + 0][k], b1 = Bs[tx * 4 + 1][k];
            float b2 = Bs[tx * 4 + 2][k], b3 = Bs[tx * 4 + 3][k];
            acc[0][0] += a0 * b0; acc[0][1] += a0 * b1; acc[0][2] += a0 * b2; acc[0][3] += a0 * b3;
            acc[1][0] += a1 * b0; acc[1][1] += a1 * b1; acc[1][2] += a1 * b2; acc[1][3] += a1 * b3;
            acc[2][0] += a2 * b0; acc[2][1] += a2 * b1; acc[2][2] += a2 * b2; acc[2][3] += a2 * b3;
            acc[3][0] += a3 * b0; acc[3][1] += a3 * b1; acc[3][2] += a3 * b2; acc[3][3] += a3 * b3;
        }
        __syncthreads();
    }

#pragma unroll
    for (int i = 0; i < 4; ++i)
#pragma unroll
        for (int j = 0; j < 4; ++j) {
            int col = n0 + tx * 4 + j;
            out[(size_t)(m0 + ty * 4 + i) * DOUT + col] = acc[i][j] * SF + bq[col] * BSF;
        }
}

extern "C" void kernel_launch(void* const* d_in, const int* in_sizes, int n_in,
                              void* d_out, int out_size, void* d_ws, size_t ws_size,
                              hipStream_t stream) {
    const float* x = (const float*)d_in[0];   // [8192,4096] f32
    const float* wgt = (const float*)d_in[1]; // [4096,4096] f32 (integer-valued)
    const float* bq = (const float*)d_in[2];  // [4096] f32 (integer-valued)
    float* out = (float*)d_out;

    const size_t need = (size_t)TOKENS * DIN + (size_t)DOUT * DIN + (size_t)DOUT * sizeof(float);

    if (d_ws != nullptr && ws_size >= need) {
        signed char* xq = (signed char*)d_ws;
        signed char* wq = xq + (size_t)TOKENS * DIN;
        float* beta = (float*)(wq + (size_t)DOUT * DIN);

        quant_x<<<2048, 256, 0, stream>>>(x, xq);
        prep_w<<<DOUT, 256, 0, stream>>>(wgt, bq, wq, beta);
        gemm_i8<<<(TOKENS / BM) * (DOUT / BN), 512, 0, stream>>>(xq, wq, beta, out);
    } else {
        gemm_fb<<<(TOKENS / 64) * (DOUT / 64), 256, 0, stream>>>(x, wgt, bq, out);
    }
}

// Round 9
// 403.648 us; speedup vs baseline: 1.3051x; 1.0115x over previous
//
#include <hip/hip_runtime.h>
#include <hip/hip_bf16.h>
#include <stdint.h>

// QuantizedLinear: out = (Q(x)-zp) @ W^T * (IN_SCALE*W_SCALE) + b*1e-4
// R9: (a) bank-conflict-free LDS swizzle: slot s of row r stored at s^((r>>1)&3)
//     (old (r&3) xor ignored the 128B bank period -> 12.6M conflicts);
//     (b) phase-interleaved K-loop: 4 x {2 ds_read ; 8 MFMA} per iter, ONE barrier
//     + ONE counted vmcnt(8) per iter (4-deep ring makes intra-iter sync unnecessary),
//     so the LDS pipe (~1280cyc/iter) overlaps the MFMA pipe (~1242cyc/iter) instead
//     of alternating (measured 38% MfmaUtil, 2907cyc/iter).

#define TOKENS 8192
#define DIN    4096
#define DOUT   4096

typedef int v4i __attribute__((ext_vector_type(4)));

#define IN_SCALE_F ((float)(2.0/255.0))
#define SF  ((float)((2.0/255.0)*0.01))   // IN_SCALE*W_SCALE
#define BSF (1e-4f)

typedef const __attribute__((address_space(1))) void* gas_ptr;
typedef __attribute__((address_space(3))) void* las_ptr;
#define GLL16(g, s) __builtin_amdgcn_global_load_lds((gas_ptr)(g), (las_ptr)(s), 16, 0, 0)

// ---------------- quantize X: f32 -> int8 (x_q - 128) ----------------
__device__ __forceinline__ int quant1(float x) {
    float v = rintf(x / IN_SCALE_F + 127.0f);   // round-half-even, zp=127
    v = fminf(fmaxf(v, 0.0f), 255.0f);
    return (int)v - 128;
}

__global__ void quant_x(const float* __restrict__ x, signed char* __restrict__ xq) {
    const int n4 = TOKENS * DIN / 4;
    const float4* x4 = (const float4*)x;
    int* o4 = (int*)xq;
    int i = blockIdx.x * blockDim.x + threadIdx.x;
    int stride = gridDim.x * blockDim.x;
    for (; i < n4; i += stride) {
        float4 v = x4[i];
        int q0 = quant1(v.x), q1 = quant1(v.y), q2 = quant1(v.z), q3 = quant1(v.w);
        o4[i] = (q0 & 255) | ((q1 & 255) << 8) | ((q2 & 255) << 16) | ((q3 & 255) << 24);
    }
}

// ------------- prep W: f32 -> int8, row sums -> beta -------------
__global__ void prep_w(const float* __restrict__ w, const float* __restrict__ bq,
                       signed char* __restrict__ wq, float* __restrict__ beta) {
    int row = blockIdx.x, t = threadIdx.x;
    const float4* wrow = (const float4*)(w + (size_t)row * DIN);
    int* wqrow = (int*)(wq + (size_t)row * DIN);
    int s = 0;
#pragma unroll
    for (int it = 0; it < 4; ++it) {
        int idx = it * 256 + t;                  // covers 0..1023
        float4 v = wrow[idx];
        int a0 = (int)v.x, a1 = (int)v.y, a2 = (int)v.z, a3 = (int)v.w;
        s += a0 + a1 + a2 + a3;
        wqrow[idx] = (a0 & 255) | ((a1 & 255) << 8) | ((a2 & 255) << 16) | ((a3 & 255) << 24);
    }
#pragma unroll
    for (int off = 32; off > 0; off >>= 1) s += __shfl_down(s, off);
    __shared__ int red[4];
    if ((t & 63) == 0) red[t >> 6] = s;
    __syncthreads();
    if (t == 0) beta[row] = (float)(red[0] + red[1] + red[2] + red[3]) * SF + bq[row] * BSF;
}

// ---------------- i8 GEMM: 256x256 tile, BK=64, 4-deep ring, 4-phase interleave ----------------
#define BM 256
#define BN 256
#define BKI 64
#define NT (DIN / BKI)          // 64 K-tiles
#define BUFB 32768              // bytes per ring buffer (A 16K + B 16K)

__global__ __launch_bounds__(512, 2) void gemm_i8(const signed char* __restrict__ A,
                                                  const signed char* __restrict__ B,
                                                  const float* __restrict__ beta,
                                                  float* __restrict__ out) {
    __shared__ signed char lds[4 * BUFB];       // 128 KB
    const int tid = threadIdx.x;
    const int w = tid >> 6, l = tid & 63;
    const int wm = w >> 2, wn = w & 3;          // wave grid 2M x 4N

    // XCD-aware bijective swizzle: 512 blocks, 512 % 8 == 0
    const int bid = blockIdx.x;
    const int swz = (bid & 7) * 64 + (bid >> 3);
    const int bm = swz >> 4;                    // 32 M-tiles
    const int bn = swz & 15;                    // 16 N-tiles
    const int m0 = bm * BM, n0 = bn * BN;

    // ---- staging: LDS dest linear (GLL constraint); global src inverse-swizzled.
    // LDS row = tid>>2 (+128 for call 1), stored slot' = tid&3 holds global slot
    // s = (tid&3) ^ ((row>>1)&3) = (tid&3) ^ ((tid>>3)&3)  (row+128 preserves xor).
    const int row0 = tid >> 2;
    const size_t src0 = (size_t)row0 * DIN + (size_t)(((tid & 3) ^ ((tid >> 3) & 3)) * 16);
    const size_t src1 = src0 + (size_t)128 * DIN;
    const unsigned l0 = (unsigned)tid * 16;
    const unsigned l1 = 8192 + (unsigned)tid * 16;
    const signed char* Abase = A + (size_t)m0 * DIN;
    const signed char* Bbase = B + (size_t)n0 * DIN;

#define STAGE(tb, kk) do {                                        \
        const signed char* _a = Abase + (kk);                     \
        const signed char* _b = Bbase + (kk);                     \
        signed char* _l = lds + (tb) * BUFB;                      \
        GLL16(_a + src0, _l + l0);                                \
        GLL16(_a + src1, _l + l1);                                \
        GLL16(_b + src0, _l + 16384 + l0);                        \
        GLL16(_b + src1, _l + 16384 + l1);                        \
    } while (0)

    // ---- fragment reads: lane l wants k-slot (l>>4) of row (l&15)+16*mf.
    // Stored at slot' = (l>>4) ^ (((l&15)>>1)&3) = (l>>4) ^ ((l>>1)&3); the xor is
    // invariant under +16*mf / +64*wn / +128 offsets (all ≡ 0 mod 4 after >>1).
    const int xslot = (l >> 4) ^ ((l >> 1) & 3);
    const unsigned abase = (unsigned)(wm * 8192 + (l & 15) * 64 + xslot * 16);
    const unsigned bbase = (unsigned)(16384 + wn * 4096 + (l & 15) * 64 + xslot * 16);

    v4i acc[8][4];
#pragma unroll
    for (int mf = 0; mf < 8; ++mf)
#pragma unroll
        for (int nf = 0; nf < 4; ++nf) acc[mf][nf] = (v4i)0;

    // prologue: stage tiles 0,1,2; wait tile 0 (12 in flight -> 8) so iter 0 reads run
    STAGE(0, 0);
    STAGE(1, BKI);
    STAGE(2, 2 * BKI);
    asm volatile("s_waitcnt vmcnt(8)" ::: "memory");
    __builtin_amdgcn_s_barrier();

#define RD(off) (*(const v4i*)(Lc + (off)))
#define PHASE(g, afA, afB)                                                             \
    __builtin_amdgcn_sched_barrier(0);                                                 \
    __builtin_amdgcn_s_setprio(1);                                                     \
    _Pragma("unroll")                                                                  \
    for (int nf = 0; nf < 4; ++nf) {                                                   \
        acc[2*(g)][nf]   = __builtin_amdgcn_mfma_i32_16x16x64_i8(afA, bf[nf], acc[2*(g)][nf],   0, 0, 0); \
        acc[2*(g)+1][nf] = __builtin_amdgcn_mfma_i32_16x16x64_i8(afB, bf[nf], acc[2*(g)+1][nf], 0, 0, 0); \
    }                                                                                  \
    __builtin_amdgcn_s_setprio(0);

#pragma unroll 4
    for (int t = 0; t < NT; ++t) {
        const int ts = t + 3;
        STAGE(ts & 3, (ts & (NT - 1)) * BKI);   // wrap staging: uniform vmcnt, dead data safe

        const signed char* Lc = lds + (t & 3) * BUFB;
        // phase 0: its own operands (only front-stall of the iter)
        v4i af0 = RD(abase), af1 = RD(abase + 1024);
        v4i bf[4] = { RD(bbase), RD(bbase + 1024), RD(bbase + 2048), RD(bbase + 3072) };
        PHASE(0, af0, af1)
        // phase 1..3: reads issued before the previous phase's MFMAs retire
        v4i af2 = RD(abase + 2048), af3 = RD(abase + 3072);
        PHASE(1, af2, af3)
        v4i af4 = RD(abase + 4096), af5 = RD(abase + 5120);
        PHASE(2, af4, af5)
        v4i af6 = RD(abase + 6144), af7 = RD(abase + 7168);
        PHASE(3, af6, af7)

        // tile t+1 landed (outstanding {t+1,t+2,t+3}=12 -> 8); buffer (t+3)&3 free
        asm volatile("s_waitcnt vmcnt(8)" ::: "memory");
        __builtin_amdgcn_s_barrier();
        __builtin_amdgcn_sched_barrier(0);
    }
#undef PHASE
#undef RD
#undef STAGE

    // epilogue: D[row=(l>>4)*4+r][col=l&15] per 16x16 frag
    const int col0 = n0 + wn * 64 + (l & 15);
    const int row0o = m0 + wm * 128 + (l >> 4) * 4;
#pragma unroll
    for (int nf = 0; nf < 4; ++nf) {
        const float bb = beta[col0 + nf * 16];
#pragma unroll
        for (int mf = 0; mf < 8; ++mf) {
#pragma unroll
            for (int r = 0; r < 4; ++r) {
                out[(size_t)(row0o + mf * 16 + r) * DOUT + (col0 + nf * 16)] =
                    (float)acc[mf][nf][r] * SF + bb;
            }
        }
    }
}

// ---------------- ws-free fallback: fused-quant f32 GEMM ----------------
__global__ __launch_bounds__(256) void gemm_fb(const float* __restrict__ x,
                                               const float* __restrict__ wgt,
                                               const float* __restrict__ bq,
                                               float* __restrict__ out) {
    __shared__ float As[64][33];
    __shared__ float Bs[64][33];
    const int t = threadIdx.x;
    const int bn = blockIdx.x & 63;
    const int bm = blockIdx.x >> 6;
    const int m0 = bm * 64, n0 = bn * 64;
    const int ty = t >> 4, tx = t & 15;

    float acc[4][4] = {{0.f}};

    for (int k0 = 0; k0 < DIN; k0 += 32) {
#pragma unroll
        for (int i = 0; i < 8; ++i) {
            int li = t * 8 + i;
            int r = li >> 5, c = li & 31;
            float v = x[(size_t)(m0 + r) * DIN + k0 + c];
            float q = fminf(fmaxf(rintf(v / IN_SCALE_F + 127.0f), 0.0f), 255.0f) - 127.0f;
            As[r][c] = q;
            Bs[r][c] = wgt[(size_t)(n0 + r) * DIN + k0 + c];
        }
        __syncthreads();
#pragma unroll 8
        for (int k = 0; k < 32; ++k) {
            float a0 = As[ty * 4 + 0][k], a1 = As[ty * 4 + 1][k];
            float a2 = As[ty * 4 + 2][k], a3 = As[ty * 4 + 3][k];
            float b0 = Bs[tx * 4 + 0][k], b1 = Bs[tx * 4 + 1][k];
            float b2 = Bs[tx * 4 + 2][k], b3 = Bs[tx * 4 + 3][k];
            acc[0][0] += a0 * b0; acc[0][1] += a0 * b1; acc[0][2] += a0 * b2; acc[0][3] += a0 * b3;
            acc[1][0] += a1 * b0; acc[1][1] += a1 * b1; acc[1][2] += a1 * b2; acc[1][3] += a1 * b3;
            acc[2][0] += a2 * b0; acc[2][1] += a2 * b1; acc[2][2] += a2 * b2; acc[2][3] += a2 * b3;
            acc[3][0] += a3 * b0; acc[3][1] += a3 * b1; acc[3][2] += a3 * b2; acc[3][3] += a3 * b3;
        }
        __syncthreads();
    }

#pragma unroll
    for (int i = 0; i < 4; ++i)
#pragma unroll
        for (int j = 0; j < 4; ++j) {
            int col = n0 + tx * 4 + j;
            out[(size_t)(m0 + ty * 4 + i) * DOUT + col] = acc[i][j] * SF + bq[col] * BSF;
        }
}

extern "C" void kernel_launch(void* const* d_in, const int* in_sizes, int n_in,
                              void* d_out, int out_size, void* d_ws, size_t ws_size,
                              hipStream_t stream) {
    const float* x = (const float*)d_in[0];   // [8192,4096] f32
    const float* wgt = (const float*)d_in[1]; // [4096,4096] f32 (integer-valued)
    const float* bq = (const float*)d_in[2];  // [4096] f32 (integer-valued)
    float* out = (float*)d_out;

    const size_t need = (size_t)TOKENS * DIN + (size_t)DOUT * DIN + (size_t)DOUT * sizeof(float);

    if (d_ws != nullptr && ws_size >= need) {
        signed char* xq = (signed char*)d_ws;
        signed char* wq = xq + (size_t)TOKENS * DIN;
        float* beta = (float*)(wq + (size_t)DOUT * DIN);

        quant_x<<<2048, 256, 0, stream>>>(x, xq);
        prep_w<<<DOUT, 256, 0, stream>>>(wgt, bq, wq, beta);
        gemm_i8<<<(TOKENS / BM) * (DOUT / BN), 512, 0, stream>>>(xq, wq, beta, out);
    } else {
        gemm_fb<<<(TOKENS / 64) * (DOUT / 64), 256, 0, stream>>>(x, wgt, bq, out);
    }
}